// Round 2
// baseline (1660.506 us; speedup 1.0000x reference)
//
#include <hip/hip_runtime.h>
#include <stdint.h>

// ---- problem constants (fixed by the reference) ----
#define B_ 4
#define T_ 1024
#define C_ 768
#define H_ 12
#define D_ 64
#define F_ 3072
#define V_ 32000
#define L_ 4

typedef unsigned short ushort_t;
typedef __bf16 bf16x8 __attribute__((ext_vector_type(8)));
typedef float f32x4 __attribute__((ext_vector_type(4)));
typedef unsigned short u16x8 __attribute__((ext_vector_type(8)));

__device__ __forceinline__ float b2f(unsigned short u) {
    union { unsigned int i; float f; } x; x.i = ((unsigned int)u) << 16; return x.f;
}
__device__ __forceinline__ unsigned short f2b(float f) {
    union { float f; unsigned int i; } x; x.f = f;
    unsigned int r = x.i + 0x7FFFu + ((x.i >> 16) & 1u);
    return (unsigned short)(r >> 16);
}

// ---------------------------------------------------------------------------
// embedding: x[b,t,c] = tok_emb[idx[b,t],c] + pos_emb[t,c]   (all f32)
// each thread: 4 contiguous c (float4)
// ---------------------------------------------------------------------------
__global__ __launch_bounds__(256) void k_embed(const int* __restrict__ idx,
        const float* __restrict__ tok, const float* __restrict__ pos,
        float* __restrict__ x) {
    int i = blockIdx.x * 256 + threadIdx.x;      // chunk of 4 elems
    int m = i / (C_ / 4);                        // token index b*T+t
    int cc = (i % (C_ / 4)) * 4;
    int t = m & (T_ - 1);
    int tokid = idx[m];
    float4 te = *(const float4*)&tok[(size_t)tokid * C_ + cc];
    float4 pe = *(const float4*)&pos[(size_t)t * C_ + cc];
    float4 o = make_float4(te.x + pe.x, te.y + pe.y, te.z + pe.z, te.w + pe.w);
    *(float4*)&x[(size_t)m * C_ + cc] = o;
}

// ---------------------------------------------------------------------------
// LayerNorm: f32 in -> bf16 out.  one row (768) per block of 256.
// ---------------------------------------------------------------------------
__global__ __launch_bounds__(256) void k_ln(const float* __restrict__ x,
        const float* __restrict__ s, const float* __restrict__ b,
        ushort_t* __restrict__ out) {
    __shared__ float red[8];
    const int row = blockIdx.x, tid = threadIdx.x;
    const float* xr = x + (size_t)row * C_;
    float v[3];
    float sum = 0.f, sq = 0.f;
#pragma unroll
    for (int j = 0; j < 3; ++j) { v[j] = xr[tid + j * 256]; sum += v[j]; sq += v[j] * v[j]; }
#pragma unroll
    for (int off = 32; off >= 1; off >>= 1) {
        sum += __shfl_down(sum, off);
        sq  += __shfl_down(sq,  off);
    }
    const int lane = tid & 63, wave = tid >> 6;
    if (lane == 0) { red[wave] = sum; red[4 + wave] = sq; }
    __syncthreads();
    if (tid < 2) {
        float a = red[tid * 4] + red[tid * 4 + 1] + red[tid * 4 + 2] + red[tid * 4 + 3];
        red[tid * 4] = a;
    }
    __syncthreads();
    float mean = red[0] * (1.f / C_);
    float var  = red[4] * (1.f / C_) - mean * mean;
    float rstd = rsqrtf(var + 1e-5f);
#pragma unroll
    for (int j = 0; j < 3; ++j) {
        int c = tid + j * 256;
        float val = (v[j] - mean) * rstd * s[c] + b[c];
        out[(size_t)row * C_ + c] = f2b(val);
    }
}

// ---------------------------------------------------------------------------
// weight transpose+convert: f32 [R,C] -> bf16 [C,R].  block (32,8), 32x32 tiles.
// ---------------------------------------------------------------------------
__global__ void k_transpose_cvt(const float* __restrict__ in, ushort_t* __restrict__ out,
                                int R, int C) {
    __shared__ float tile[32][33];
    int r0 = blockIdx.y * 32, c0 = blockIdx.x * 32;
    int tx = threadIdx.x, ty = threadIdx.y;
#pragma unroll
    for (int i = ty; i < 32; i += 8)
        tile[i][tx] = in[(size_t)(r0 + i) * C + c0 + tx];
    __syncthreads();
#pragma unroll
    for (int i = ty; i < 32; i += 8)
        out[(size_t)(c0 + i) * R + r0 + tx] = f2b(tile[tx][i]);
}

// ---------------------------------------------------------------------------
// bf16 transpose [R,C] -> [C,R], batched over blockIdx.z (stride R*C both).
// ---------------------------------------------------------------------------
__global__ void k_transpose_b(const ushort_t* __restrict__ in, ushort_t* __restrict__ out,
                              int R, int C) {
    __shared__ ushort_t tile[32][33];
    size_t base = (size_t)blockIdx.z * R * C;
    int r0 = blockIdx.y * 32, c0 = blockIdx.x * 32;
    int tx = threadIdx.x, ty = threadIdx.y;
#pragma unroll
    for (int i = ty; i < 32; i += 8)
        tile[i][tx] = in[base + (size_t)(r0 + i) * C + c0 + tx];
    __syncthreads();
#pragma unroll
    for (int i = ty; i < 32; i += 8)
        out[base + (size_t)(c0 + i) * R + r0 + tx] = tile[tx][i];
}

// ---------------------------------------------------------------------------
// GEMM  C[M,N] = A[M,K] @ BT[N,K]^T   (both K-contiguous bf16), MFMA 16x16x32
// 128x128 tile, BK=32, 4 waves (2x2), 4x4 fragments/wave, reg-staged LDS.
// EPI: 0 = f32 store (head)       1 = +bias, GELU(exact), bf16 store
//      2 = +bias +resid(f32), f32 store (in-place x ok)
//      3 = scatter to [B,H,T,D] bf16 (QKV)
// ---------------------------------------------------------------------------
template <int EPI>
__global__ __launch_bounds__(256) void k_gemm(
        const ushort_t* __restrict__ A, const ushort_t* __restrict__ BT,
        const float* __restrict__ bias, const float* __restrict__ resid,
        float* __restrict__ outf, ushort_t* __restrict__ outb,
        int M, int N, int K) {
    __shared__ __align__(16) ushort_t As[128 * 32];
    __shared__ __align__(16) ushort_t Bs[128 * 32];
    const int tid = threadIdx.x;
    const int lane = tid & 63, wave = tid >> 6;
    const int lr = lane & 15, lg = lane >> 4;
    const int wm = (wave >> 1) * 64, wn = (wave & 1) * 64;
    const int m0 = blockIdx.y * 128, n0 = blockIdx.x * 128;

    f32x4 acc[4][4];
#pragma unroll
    for (int i = 0; i < 4; ++i)
#pragma unroll
        for (int j = 0; j < 4; ++j) acc[i][j] = (f32x4){0.f, 0.f, 0.f, 0.f};

    for (int k0 = 0; k0 < K; k0 += 32) {
#pragma unroll
        for (int c = 0; c < 2; ++c) {
            int chunk = c * 256 + tid;          // 0..511
            int row = chunk >> 2;               // 0..127
            int kk = (chunk & 3) << 3;          // 0,8,16,24
            *(u16x8*)&As[row * 32 + kk] = *(const u16x8*)&A[(size_t)(m0 + row) * K + k0 + kk];
            *(u16x8*)&Bs[row * 32 + kk] = *(const u16x8*)&BT[(size_t)(n0 + row) * K + k0 + kk];
        }
        __syncthreads();
        bf16x8 af[4], bfr[4];
#pragma unroll
        for (int i = 0; i < 4; ++i) af[i]  = *(const bf16x8*)&As[(wm + i * 16 + lr) * 32 + lg * 8];
#pragma unroll
        for (int j = 0; j < 4; ++j) bfr[j] = *(const bf16x8*)&Bs[(wn + j * 16 + lr) * 32 + lg * 8];
#pragma unroll
        for (int i = 0; i < 4; ++i)
#pragma unroll
            for (int j = 0; j < 4; ++j)
                acc[i][j] = __builtin_amdgcn_mfma_f32_16x16x32_bf16(af[i], bfr[j], acc[i][j], 0, 0, 0);
        __syncthreads();
    }

#pragma unroll
    for (int i = 0; i < 4; ++i) {
#pragma unroll
        for (int j = 0; j < 4; ++j) {
            int col = n0 + wn + j * 16 + lr;
            float bval = 0.f;
            if (EPI == 1 || EPI == 2) bval = bias[col];
#pragma unroll
            for (int r = 0; r < 4; ++r) {
                int row = m0 + wm + i * 16 + lg * 4 + r;
                float v = acc[i][j][r];
                if (EPI == 0) {
                    outf[(size_t)row * N + col] = v;
                } else if (EPI == 1) {
                    float u = v + bval;
                    float g = 0.5f * u * (1.0f + erff(u * 0.70710678118654752f));
                    outb[(size_t)row * N + col] = f2b(g);
                } else if (EPI == 2) {
                    outf[(size_t)row * N + col] = resid[(size_t)row * N + col] + v + bval;
                } else {
                    int bb = row >> 10, t = row & 1023;
                    int hh = col >> 6, d = col & 63;
                    outb[((((size_t)bb * H_ + hh) << 10) + t) * D_ + d] = f2b(v);
                }
            }
        }
    }
}

// ---------------------------------------------------------------------------
// flash attention: q,k [BH,T,D] bf16, vT [BH,D,T] bf16 -> y [BH,T,D] bf16
// block = 4 waves, wave = 16 q rows, KV tiles of 32, online softmax (f32).
// ---------------------------------------------------------------------------
__global__ __launch_bounds__(256) void k_attn(const ushort_t* __restrict__ q,
        const ushort_t* __restrict__ k, const ushort_t* __restrict__ vT,
        ushort_t* __restrict__ y) {
    __shared__ __align__(16) ushort_t P[4][16 * 32];
    const int lane = threadIdx.x & 63, wave = threadIdx.x >> 6;
    const int lr = lane & 15, lg = lane >> 4;
    const int bh = blockIdx.x;
    const int qrow0 = blockIdx.y * 64 + wave * 16;
    const ushort_t* qb = q + (size_t)bh * T_ * D_;
    const ushort_t* kb = k + (size_t)bh * T_ * D_;
    const ushort_t* vb = vT + (size_t)bh * D_ * T_;

    bf16x8 aq0 = *(const bf16x8*)&qb[(qrow0 + lr) * D_ + lg * 8];
    bf16x8 aq1 = *(const bf16x8*)&qb[(qrow0 + lr) * D_ + 32 + lg * 8];

    f32x4 accY[4];
    float mr[4], ls[4];
#pragma unroll
    for (int d = 0; d < 4; ++d) accY[d] = (f32x4){0.f, 0.f, 0.f, 0.f};
#pragma unroll
    for (int r = 0; r < 4; ++r) { mr[r] = -1e30f; ls[r] = 0.f; }

    ushort_t* pw = &P[wave][0];
    const int kv_end = qrow0 + 16;
    for (int kv0 = 0; kv0 < kv_end; kv0 += 32) {
        f32x4 s0 = (f32x4){0.f, 0.f, 0.f, 0.f};
        f32x4 s1 = (f32x4){0.f, 0.f, 0.f, 0.f};
        bf16x8 bk;
        bk = *(const bf16x8*)&kb[(kv0 + lr) * D_ + lg * 8];
        s0 = __builtin_amdgcn_mfma_f32_16x16x32_bf16(aq0, bk, s0, 0, 0, 0);
        bk = *(const bf16x8*)&kb[(kv0 + lr) * D_ + 32 + lg * 8];
        s0 = __builtin_amdgcn_mfma_f32_16x16x32_bf16(aq1, bk, s0, 0, 0, 0);
        bk = *(const bf16x8*)&kb[(kv0 + 16 + lr) * D_ + lg * 8];
        s1 = __builtin_amdgcn_mfma_f32_16x16x32_bf16(aq0, bk, s1, 0, 0, 0);
        bk = *(const bf16x8*)&kb[(kv0 + 16 + lr) * D_ + 32 + lg * 8];
        s1 = __builtin_amdgcn_mfma_f32_16x16x32_bf16(aq1, bk, s1, 0, 0, 0);

        const int col0 = kv0 + lr, col1 = kv0 + 16 + lr;
        float p0[4], p1[4], so[4];
#pragma unroll
        for (int r = 0; r < 4; ++r) {
            int row = qrow0 + lg * 4 + r;
            float a0 = (col0 <= row) ? s0[r] * 0.125f : -1e30f;
            float a1 = (col1 <= row) ? s1[r] * 0.125f : -1e30f;
            float t = fmaxf(a0, a1);
            t = fmaxf(t, __shfl_xor(t, 1));
            t = fmaxf(t, __shfl_xor(t, 2));
            t = fmaxf(t, __shfl_xor(t, 4));
            t = fmaxf(t, __shfl_xor(t, 8));
            float mn = fmaxf(mr[r], t);
            so[r] = __expf(mr[r] - mn);
            p0[r] = __expf(a0 - mn);
            p1[r] = __expf(a1 - mn);
            float ps = p0[r] + p1[r];
            ps += __shfl_xor(ps, 1);
            ps += __shfl_xor(ps, 2);
            ps += __shfl_xor(ps, 4);
            ps += __shfl_xor(ps, 8);
            ls[r] = ls[r] * so[r] + ps;
            mr[r] = mn;
        }
#pragma unroll
        for (int d = 0; d < 4; ++d)
#pragma unroll
            for (int r = 0; r < 4; ++r) accY[d][r] *= so[r];

        // previous iter's P read must be complete before overwrite
        asm volatile("s_waitcnt lgkmcnt(0)" ::: "memory");
        __builtin_amdgcn_sched_barrier(0);
#pragma unroll
        for (int r = 0; r < 4; ++r) {
            pw[(lg * 4 + r) * 32 + lr]      = f2b(p0[r]);
            pw[(lg * 4 + r) * 32 + 16 + lr] = f2b(p1[r]);
        }
        asm volatile("s_waitcnt lgkmcnt(0)" ::: "memory");
        __builtin_amdgcn_sched_barrier(0);
        bf16x8 pa = *(const bf16x8*)&pw[lr * 32 + lg * 8];
#pragma unroll
        for (int d = 0; d < 4; ++d) {
            bf16x8 bv = *(const bf16x8*)&vb[(d * 16 + lr) * T_ + kv0 + lg * 8];
            accY[d] = __builtin_amdgcn_mfma_f32_16x16x32_bf16(pa, bv, accY[d], 0, 0, 0);
        }
    }
#pragma unroll
    for (int d = 0; d < 4; ++d)
#pragma unroll
        for (int r = 0; r < 4; ++r) {
            int row = qrow0 + lg * 4 + r;
            y[((size_t)bh * T_ + row) * D_ + d * 16 + lr] = f2b(accY[d][r] / ls[r]);
        }
}

// ---------------------------------------------------------------------------
// gather heads: y [B,H,T,D] -> ycat [B*T, C]
// ---------------------------------------------------------------------------
__global__ __launch_bounds__(256) void k_ycat(const ushort_t* __restrict__ y,
                                              ushort_t* __restrict__ yc) {
    int i = blockIdx.x * 256 + threadIdx.x;      // chunk of 8
    int m = i / (C_ / 8);
    int cc = (i % (C_ / 8)) * 8;
    int b = m >> 10, t = m & 1023;
    int hh = cc >> 6, d = cc & 63;
    *(u16x8*)&yc[(size_t)m * C_ + cc] =
        *(const u16x8*)&y[((((size_t)b * H_ + hh) << 10) + t) * D_ + d];
}

// ---------------------------------------------------------------------------
extern "C" void kernel_launch(void* const* d_in, const int* in_sizes, int n_in,
                              void* d_out, int out_size, void* d_ws, size_t ws_size,
                              hipStream_t stream) {
    (void)in_sizes; (void)n_in; (void)out_size; (void)ws_size;
    const int*   idx  = (const int*)d_in[0];
    const float* tok  = (const float*)d_in[1];
    const float* pos  = (const float*)d_in[2];
    const float* Wq   = (const float*)d_in[3];
    const float* Wk   = (const float*)d_in[4];
    const float* Wv   = (const float*)d_in[5];
    const float* Wp   = (const float*)d_in[6];
    const float* bp   = (const float*)d_in[7];
    const float* ln1s = (const float*)d_in[8];
    const float* ln1b = (const float*)d_in[9];
    const float* ln2s = (const float*)d_in[10];
    const float* ln2b = (const float*)d_in[11];
    const float* W1   = (const float*)d_in[12];
    const float* b1   = (const float*)d_in[13];
    const float* W2   = (const float*)d_in[14];
    const float* b2   = (const float*)d_in[15];
    const float* lnfs = (const float*)d_in[16];
    const float* lnfb = (const float*)d_in[17];
    const float* Wh   = (const float*)d_in[18];
    float* out = (float*)d_out;

    char* ws = (char*)d_ws;
    size_t off = 0;
    auto alloc = [&](size_t bytes) { void* p = ws + off; off += (bytes + 255) & ~(size_t)255; return p; };

    ushort_t* wTa  = (ushort_t*)alloc((size_t)C_ * C_ * 2);   // per-layer q/k/v/p slot
    ushort_t* wT1  = (ushort_t*)alloc((size_t)C_ * F_ * 2);
    ushort_t* wT2  = (ushort_t*)alloc((size_t)F_ * C_ * 2);
    ushort_t* whT  = (ushort_t*)alloc((size_t)C_ * V_ * 2);
    float*    x    = (float*)   alloc((size_t)B_ * T_ * C_ * 4);
    ushort_t* h    = (ushort_t*)alloc((size_t)B_ * T_ * C_ * 2);
    ushort_t* qb_  = (ushort_t*)alloc((size_t)B_ * T_ * C_ * 2);
    ushort_t* kb_  = (ushort_t*)alloc((size_t)B_ * T_ * C_ * 2);
    ushort_t* vb_  = (ushort_t*)alloc((size_t)B_ * T_ * C_ * 2);
    ushort_t* vTb  = (ushort_t*)alloc((size_t)B_ * T_ * C_ * 2);
    ushort_t* yb   = (ushort_t*)alloc((size_t)B_ * T_ * C_ * 2);
    ushort_t* ycat = (ushort_t*)alloc((size_t)B_ * T_ * C_ * 2);
    ushort_t* mh   = (ushort_t*)alloc((size_t)B_ * T_ * F_ * 2);

    dim3 tb(32, 8);
    k_embed<<<3072, 256, 0, stream>>>(idx, tok, pos, x);

    for (int l = 0; l < L_; ++l) {
        k_ln<<<4096, 256, 0, stream>>>(x, ln1s + l * C_, ln1b + l * C_, h);
        k_transpose_cvt<<<dim3(24, 24), tb, 0, stream>>>(Wq + (size_t)l * C_ * C_, wTa, C_, C_);
        k_gemm<3><<<dim3(6, 32), 256, 0, stream>>>(h, wTa, nullptr, nullptr, nullptr, qb_, 4096, C_, C_);
        k_transpose_cvt<<<dim3(24, 24), tb, 0, stream>>>(Wk + (size_t)l * C_ * C_, wTa, C_, C_);
        k_gemm<3><<<dim3(6, 32), 256, 0, stream>>>(h, wTa, nullptr, nullptr, nullptr, kb_, 4096, C_, C_);
        k_transpose_cvt<<<dim3(24, 24), tb, 0, stream>>>(Wv + (size_t)l * C_ * C_, wTa, C_, C_);
        k_gemm<3><<<dim3(6, 32), 256, 0, stream>>>(h, wTa, nullptr, nullptr, nullptr, vb_, 4096, C_, C_);
        k_transpose_b<<<dim3(2, 32, 48), tb, 0, stream>>>(vb_, vTb, T_, D_);
        k_attn<<<dim3(48, 16), 256, 0, stream>>>(qb_, kb_, vTb, yb);
        k_ycat<<<1536, 256, 0, stream>>>(yb, ycat);
        k_transpose_cvt<<<dim3(24, 24), tb, 0, stream>>>(Wp + (size_t)l * C_ * C_, wTa, C_, C_);
        k_gemm<2><<<dim3(6, 32), 256, 0, stream>>>(ycat, wTa, bp + l * C_, x, x, nullptr, 4096, C_, C_);
        k_ln<<<4096, 256, 0, stream>>>(x, ln2s + l * C_, ln2b + l * C_, h);
        k_transpose_cvt<<<dim3(96, 24), tb, 0, stream>>>(W1 + (size_t)l * C_ * F_, wT1, C_, F_);
        k_gemm<1><<<dim3(24, 32), 256, 0, stream>>>(h, wT1, b1 + l * F_, nullptr, nullptr, mh, 4096, F_, C_);
        k_transpose_cvt<<<dim3(24, 96), tb, 0, stream>>>(W2 + (size_t)l * F_ * C_, wT2, F_, C_);
        k_gemm<2><<<dim3(6, 32), 256, 0, stream>>>(mh, wT2, b2 + l * C_, x, x, nullptr, 4096, C_, F_);
    }
    k_ln<<<4096, 256, 0, stream>>>(x, lnfs, lnfb, h);
    k_transpose_cvt<<<dim3(1000, 24), tb, 0, stream>>>(Wh, whT, C_, V_);
    k_gemm<0><<<dim3(250, 32), 256, 0, stream>>>(h, whT, nullptr, nullptr, out, nullptr, 4096, V_, C_);
}

// Round 3
// 1438.622 us; speedup vs baseline: 1.1542x; 1.1542x over previous
//
#include <hip/hip_runtime.h>
#include <stdint.h>

// ---- problem constants (fixed by the reference) ----
#define B_ 4
#define T_ 1024
#define C_ 768
#define H_ 12
#define D_ 64
#define F_ 3072
#define V_ 32000
#define L_ 4

typedef unsigned short ushort_t;
typedef __bf16 bf16x8 __attribute__((ext_vector_type(8)));
typedef float f32x4 __attribute__((ext_vector_type(4)));
typedef unsigned short u16x8 __attribute__((ext_vector_type(8)));

__device__ __forceinline__ float b2f(unsigned short u) {
    union { unsigned int i; float f; } x; x.i = ((unsigned int)u) << 16; return x.f;
}
__device__ __forceinline__ unsigned short f2b(float f) {
    union { float f; unsigned int i; } x; x.f = f;
    unsigned int r = x.i + 0x7FFFu + ((x.i >> 16) & 1u);
    return (unsigned short)(r >> 16);
}

// async global->LDS, 16B per lane; LDS dest = wave-uniform base + lane*16
__device__ __forceinline__ void gload16(const ushort_t* g, ushort_t* l) {
    __builtin_amdgcn_global_load_lds(
        (const __attribute__((address_space(1))) unsigned int*)g,
        (__attribute__((address_space(3))) unsigned int*)l, 16, 0, 0);
}

// ---------------------------------------------------------------------------
// embedding: x[b,t,c] = tok_emb[idx[b,t],c] + pos_emb[t,c]   (all f32)
// ---------------------------------------------------------------------------
__global__ __launch_bounds__(256) void k_embed(const int* __restrict__ idx,
        const float* __restrict__ tok, const float* __restrict__ pos,
        float* __restrict__ x) {
    int i = blockIdx.x * 256 + threadIdx.x;      // chunk of 4 elems
    int m = i / (C_ / 4);
    int cc = (i % (C_ / 4)) * 4;
    int t = m & (T_ - 1);
    int tokid = idx[m];
    float4 te = *(const float4*)&tok[(size_t)tokid * C_ + cc];
    float4 pe = *(const float4*)&pos[(size_t)t * C_ + cc];
    *(float4*)&x[(size_t)m * C_ + cc] =
        make_float4(te.x + pe.x, te.y + pe.y, te.z + pe.z, te.w + pe.w);
}

// ---------------------------------------------------------------------------
// LayerNorm: f32 in -> bf16 out.  one row (768) per block of 256.
// ---------------------------------------------------------------------------
__global__ __launch_bounds__(256) void k_ln(const float* __restrict__ x,
        const float* __restrict__ s, const float* __restrict__ b,
        ushort_t* __restrict__ out) {
    __shared__ float red[8];
    const int row = blockIdx.x, tid = threadIdx.x;
    const float* xr = x + (size_t)row * C_;
    float v[3];
    float sum = 0.f, sq = 0.f;
#pragma unroll
    for (int j = 0; j < 3; ++j) { v[j] = xr[tid + j * 256]; sum += v[j]; sq += v[j] * v[j]; }
#pragma unroll
    for (int off = 32; off >= 1; off >>= 1) {
        sum += __shfl_down(sum, off);
        sq  += __shfl_down(sq,  off);
    }
    const int lane = tid & 63, wave = tid >> 6;
    if (lane == 0) { red[wave] = sum; red[4 + wave] = sq; }
    __syncthreads();
    if (tid < 2) {
        float a = red[tid * 4] + red[tid * 4 + 1] + red[tid * 4 + 2] + red[tid * 4 + 3];
        red[tid * 4] = a;
    }
    __syncthreads();
    float mean = red[0] * (1.f / C_);
    float var  = red[4] * (1.f / C_) - mean * mean;
    float rstd = rsqrtf(var + 1e-5f);
#pragma unroll
    for (int j = 0; j < 3; ++j) {
        int c = tid + j * 256;
        out[(size_t)row * C_ + c] = f2b((v[j] - mean) * rstd * s[c] + b[c]);
    }
}

// ---------------------------------------------------------------------------
// weight transpose+convert: f32 [R,C] -> bf16 [C,R].  block (32,8), 32x32 tiles.
// ---------------------------------------------------------------------------
__global__ void k_transpose_cvt(const float* __restrict__ in, ushort_t* __restrict__ out,
                                int R, int C) {
    __shared__ float tile[32][33];
    int r0 = blockIdx.y * 32, c0 = blockIdx.x * 32;
    int tx = threadIdx.x, ty = threadIdx.y;
#pragma unroll
    for (int i = ty; i < 32; i += 8)
        tile[i][tx] = in[(size_t)(r0 + i) * C + c0 + tx];
    __syncthreads();
#pragma unroll
    for (int i = ty; i < 32; i += 8)
        out[(size_t)(c0 + i) * R + r0 + tx] = f2b(tile[tx][i]);
}

// batched 3-source version for Wq/Wk/Wv -> one [2304, 768] bf16 buffer
__global__ void k_transpose_cvt3(const float* __restrict__ w0, const float* __restrict__ w1,
                                 const float* __restrict__ w2, ushort_t* __restrict__ out) {
    __shared__ float tile[32][33];
    const float* in = (blockIdx.z == 0) ? w0 : (blockIdx.z == 1) ? w1 : w2;
    ushort_t* o = out + (size_t)blockIdx.z * C_ * C_;
    int r0 = blockIdx.y * 32, c0 = blockIdx.x * 32;
    int tx = threadIdx.x, ty = threadIdx.y;
#pragma unroll
    for (int i = ty; i < 32; i += 8)
        tile[i][tx] = in[(size_t)(r0 + i) * C_ + c0 + tx];
    __syncthreads();
#pragma unroll
    for (int i = ty; i < 32; i += 8)
        o[(size_t)(c0 + i) * C_ + r0 + tx] = f2b(tile[tx][i]);
}

// ---------------------------------------------------------------------------
// GEMM  C[M,N] = A[M,K] @ BT[N,K]^T  (bf16, K-contiguous), MFMA 16x16x32
// 128x128 tile, BK=32, 4 waves (2x2), 4x4 frags/wave, global_load_lds staging,
// XCD-chunked block swizzle (grid must be divisible by 8).
// EPI: 0 = f32 store (head)       1 = +bias, GELU(exact), bf16 store
//      2 = +bias +resid(f32), f32 store (in-place x ok)
//      3 = QKV 3-way scatter: q,k -> [B,H,T,D], v -> [B,H,D,T] (transposed)
// ---------------------------------------------------------------------------
template <int EPI>
__global__ __launch_bounds__(256) void k_gemm(
        const ushort_t* __restrict__ A, const ushort_t* __restrict__ BT,
        const float* __restrict__ bias, const float* __restrict__ resid,
        float* __restrict__ outf, ushort_t* __restrict__ outb,
        ushort_t* __restrict__ outb2, ushort_t* __restrict__ outb3,
        int M, int N, int K) {
    __shared__ __align__(16) ushort_t As[128 * 32];
    __shared__ __align__(16) ushort_t Bs[128 * 32];
    const int tid = threadIdx.x;
    const int lane = tid & 63, wave = tid >> 6;
    const int lr = lane & 15, lg = lane >> 4;
    const int wm = (wave >> 1) * 64, wn = (wave & 1) * 64;

    // XCD-chunked swizzle: consecutive linear ids round-robin XCDs by default;
    // remap so each XCD owns a contiguous chunk (n-fastest => A-row stays in its L2).
    const int GX = gridDim.x;
    int bid = blockIdx.y * GX + blockIdx.x;
    int cpx = (GX * gridDim.y) >> 3;
    int swz = (bid & 7) * cpx + (bid >> 3);
    const int m0 = (swz / GX) * 128, n0 = (swz % GX) * 128;

    const int sr = wave * 16 + (lane >> 2);      // staging row within 64-row chunk
    const int sc = (lane & 3) << 3;              // staging col (bf16 elems)

    f32x4 acc[4][4];
#pragma unroll
    for (int i = 0; i < 4; ++i)
#pragma unroll
        for (int j = 0; j < 4; ++j) acc[i][j] = (f32x4){0.f, 0.f, 0.f, 0.f};

    for (int k0 = 0; k0 < K; k0 += 32) {
        gload16(&A [(size_t)(m0 + sr)      * K + k0 + sc], &As[sr * 32 + sc]);
        gload16(&A [(size_t)(m0 + 64 + sr) * K + k0 + sc], &As[(64 + sr) * 32 + sc]);
        gload16(&BT[(size_t)(n0 + sr)      * K + k0 + sc], &Bs[sr * 32 + sc]);
        gload16(&BT[(size_t)(n0 + 64 + sr) * K + k0 + sc], &Bs[(64 + sr) * 32 + sc]);
        __syncthreads();
        bf16x8 af[4], bfr[4];
#pragma unroll
        for (int i = 0; i < 4; ++i) af[i]  = *(const bf16x8*)&As[(wm + i * 16 + lr) * 32 + lg * 8];
#pragma unroll
        for (int j = 0; j < 4; ++j) bfr[j] = *(const bf16x8*)&Bs[(wn + j * 16 + lr) * 32 + lg * 8];
#pragma unroll
        for (int i = 0; i < 4; ++i)
#pragma unroll
            for (int j = 0; j < 4; ++j)
                acc[i][j] = __builtin_amdgcn_mfma_f32_16x16x32_bf16(af[i], bfr[j], acc[i][j], 0, 0, 0);
        __syncthreads();
    }

#pragma unroll
    for (int i = 0; i < 4; ++i) {
#pragma unroll
        for (int j = 0; j < 4; ++j) {
            int col = n0 + wn + j * 16 + lr;
            float bval = 0.f;
            if (EPI == 1 || EPI == 2) bval = bias[col];
#pragma unroll
            for (int r = 0; r < 4; ++r) {
                int row = m0 + wm + i * 16 + lg * 4 + r;
                float v = acc[i][j][r];
                if (EPI == 0) {
                    outf[(size_t)row * N + col] = v;
                } else if (EPI == 1) {
                    float u = v + bval;
                    outb[(size_t)row * N + col] =
                        f2b(0.5f * u * (1.0f + erff(u * 0.70710678118654752f)));
                } else if (EPI == 2) {
                    outf[(size_t)row * N + col] = resid[(size_t)row * N + col] + v + bval;
                } else {
                    int nm = col / 768, c = col % 768;
                    int hh = c >> 6, d = c & 63;
                    int bb = row >> 10, t = row & 1023;
                    ushort_t val = f2b(v);
                    if (nm == 0)
                        outb [((((size_t)bb * H_ + hh) << 10) + t) * D_ + d] = val;
                    else if (nm == 1)
                        outb2[((((size_t)bb * H_ + hh) << 10) + t) * D_ + d] = val;
                    else
                        outb3[(((size_t)bb * H_ + hh) * D_ + d) * T_ + t] = val;
                }
            }
        }
    }
}

// ---------------------------------------------------------------------------
// flash attention: q,k [BH,T,D] bf16, vT [BH,D,T] bf16 -> yc [B,T,C] bf16
// block = 4 waves, wave = 16 q rows, KV tiles of 32, online softmax (f32).
// output written directly in concat layout (fuses head-gather).
// ---------------------------------------------------------------------------
__global__ __launch_bounds__(256) void k_attn(const ushort_t* __restrict__ q,
        const ushort_t* __restrict__ k, const ushort_t* __restrict__ vT,
        ushort_t* __restrict__ yc) {
    __shared__ __align__(16) ushort_t P[4][16 * 32];
    const int lane = threadIdx.x & 63, wave = threadIdx.x >> 6;
    const int lr = lane & 15, lg = lane >> 4;
    const int bh = blockIdx.x;
    const int bb = bh / H_, hh = bh % H_;
    const int qrow0 = blockIdx.y * 64 + wave * 16;
    const ushort_t* qb = q + (size_t)bh * T_ * D_;
    const ushort_t* kb = k + (size_t)bh * T_ * D_;
    const ushort_t* vb = vT + (size_t)bh * D_ * T_;

    bf16x8 aq0 = *(const bf16x8*)&qb[(qrow0 + lr) * D_ + lg * 8];
    bf16x8 aq1 = *(const bf16x8*)&qb[(qrow0 + lr) * D_ + 32 + lg * 8];

    f32x4 accY[4];
    float mr[4], ls[4];
#pragma unroll
    for (int d = 0; d < 4; ++d) accY[d] = (f32x4){0.f, 0.f, 0.f, 0.f};
#pragma unroll
    for (int r = 0; r < 4; ++r) { mr[r] = -1e30f; ls[r] = 0.f; }

    ushort_t* pw = &P[wave][0];
    const int kv_end = qrow0 + 16;
    for (int kv0 = 0; kv0 < kv_end; kv0 += 32) {
        f32x4 s0 = (f32x4){0.f, 0.f, 0.f, 0.f};
        f32x4 s1 = (f32x4){0.f, 0.f, 0.f, 0.f};
        bf16x8 bk;
        bk = *(const bf16x8*)&kb[(kv0 + lr) * D_ + lg * 8];
        s0 = __builtin_amdgcn_mfma_f32_16x16x32_bf16(aq0, bk, s0, 0, 0, 0);
        bk = *(const bf16x8*)&kb[(kv0 + lr) * D_ + 32 + lg * 8];
        s0 = __builtin_amdgcn_mfma_f32_16x16x32_bf16(aq1, bk, s0, 0, 0, 0);
        bk = *(const bf16x8*)&kb[(kv0 + 16 + lr) * D_ + lg * 8];
        s1 = __builtin_amdgcn_mfma_f32_16x16x32_bf16(aq0, bk, s1, 0, 0, 0);
        bk = *(const bf16x8*)&kb[(kv0 + 16 + lr) * D_ + 32 + lg * 8];
        s1 = __builtin_amdgcn_mfma_f32_16x16x32_bf16(aq1, bk, s1, 0, 0, 0);

        const int col0 = kv0 + lr, col1 = kv0 + 16 + lr;
        float p0[4], p1[4], so[4];
#pragma unroll
        for (int r = 0; r < 4; ++r) {
            int row = qrow0 + lg * 4 + r;
            float a0 = (col0 <= row) ? s0[r] * 0.125f : -1e30f;
            float a1 = (col1 <= row) ? s1[r] * 0.125f : -1e30f;
            float t = fmaxf(a0, a1);
            t = fmaxf(t, __shfl_xor(t, 1));
            t = fmaxf(t, __shfl_xor(t, 2));
            t = fmaxf(t, __shfl_xor(t, 4));
            t = fmaxf(t, __shfl_xor(t, 8));
            float mn = fmaxf(mr[r], t);
            so[r] = __expf(mr[r] - mn);
            p0[r] = __expf(a0 - mn);
            p1[r] = __expf(a1 - mn);
            float ps = p0[r] + p1[r];
            ps += __shfl_xor(ps, 1);
            ps += __shfl_xor(ps, 2);
            ps += __shfl_xor(ps, 4);
            ps += __shfl_xor(ps, 8);
            ls[r] = ls[r] * so[r] + ps;
            mr[r] = mn;
        }
#pragma unroll
        for (int d = 0; d < 4; ++d)
#pragma unroll
            for (int r = 0; r < 4; ++r) accY[d][r] *= so[r];

        // previous iter's P read must be complete before overwrite
        asm volatile("s_waitcnt lgkmcnt(0)" ::: "memory");
        __builtin_amdgcn_sched_barrier(0);
#pragma unroll
        for (int r = 0; r < 4; ++r) {
            pw[(lg * 4 + r) * 32 + lr]      = f2b(p0[r]);
            pw[(lg * 4 + r) * 32 + 16 + lr] = f2b(p1[r]);
        }
        asm volatile("s_waitcnt lgkmcnt(0)" ::: "memory");
        __builtin_amdgcn_sched_barrier(0);
        bf16x8 pa = *(const bf16x8*)&pw[lr * 32 + lg * 8];
#pragma unroll
        for (int d = 0; d < 4; ++d) {
            bf16x8 bv = *(const bf16x8*)&vb[(d * 16 + lr) * T_ + kv0 + lg * 8];
            accY[d] = __builtin_amdgcn_mfma_f32_16x16x32_bf16(pa, bv, accY[d], 0, 0, 0);
        }
    }
#pragma unroll
    for (int d = 0; d < 4; ++d)
#pragma unroll
        for (int r = 0; r < 4; ++r) {
            int row = qrow0 + lg * 4 + r;
            yc[((size_t)bb * T_ + row) * C_ + hh * D_ + d * 16 + lr] = f2b(accY[d][r] / ls[r]);
        }
}

// ---------------------------------------------------------------------------
extern "C" void kernel_launch(void* const* d_in, const int* in_sizes, int n_in,
                              void* d_out, int out_size, void* d_ws, size_t ws_size,
                              hipStream_t stream) {
    (void)in_sizes; (void)n_in; (void)out_size; (void)ws_size;
    const int*   idx  = (const int*)d_in[0];
    const float* tok  = (const float*)d_in[1];
    const float* pos  = (const float*)d_in[2];
    const float* Wq   = (const float*)d_in[3];
    const float* Wk   = (const float*)d_in[4];
    const float* Wv   = (const float*)d_in[5];
    const float* Wp   = (const float*)d_in[6];
    const float* bp   = (const float*)d_in[7];
    const float* ln1s = (const float*)d_in[8];
    const float* ln1b = (const float*)d_in[9];
    const float* ln2s = (const float*)d_in[10];
    const float* ln2b = (const float*)d_in[11];
    const float* W1   = (const float*)d_in[12];
    const float* b1   = (const float*)d_in[13];
    const float* W2   = (const float*)d_in[14];
    const float* b2   = (const float*)d_in[15];
    const float* lnfs = (const float*)d_in[16];
    const float* lnfb = (const float*)d_in[17];
    const float* Wh   = (const float*)d_in[18];
    float* out = (float*)d_out;

    char* ws = (char*)d_ws;
    size_t off = 0;
    auto alloc = [&](size_t bytes) { void* p = ws + off; off += (bytes + 255) & ~(size_t)255; return p; };

    ushort_t* wTqkv = (ushort_t*)alloc((size_t)3 * C_ * C_ * 2);  // [2304,768]
    ushort_t* wTa   = (ushort_t*)alloc((size_t)C_ * C_ * 2);      // proj slot
    ushort_t* wT1   = (ushort_t*)alloc((size_t)C_ * F_ * 2);
    ushort_t* wT2   = (ushort_t*)alloc((size_t)F_ * C_ * 2);
    ushort_t* whT   = (ushort_t*)alloc((size_t)C_ * V_ * 2);
    float*    x     = (float*)   alloc((size_t)B_ * T_ * C_ * 4);
    ushort_t* h     = (ushort_t*)alloc((size_t)B_ * T_ * C_ * 2);
    ushort_t* qb_   = (ushort_t*)alloc((size_t)B_ * T_ * C_ * 2);
    ushort_t* kb_   = (ushort_t*)alloc((size_t)B_ * T_ * C_ * 2);
    ushort_t* vTb   = (ushort_t*)alloc((size_t)B_ * T_ * C_ * 2);
    ushort_t* yc    = (ushort_t*)alloc((size_t)B_ * T_ * C_ * 2);
    ushort_t* mh    = (ushort_t*)alloc((size_t)B_ * T_ * F_ * 2);

    dim3 tb(32, 8);
    k_embed<<<3072, 256, 0, stream>>>(idx, tok, pos, x);

    for (int l = 0; l < L_; ++l) {
        k_ln<<<4096, 256, 0, stream>>>(x, ln1s + l * C_, ln1b + l * C_, h);
        k_transpose_cvt3<<<dim3(24, 24, 3), tb, 0, stream>>>(
            Wq + (size_t)l * C_ * C_, Wk + (size_t)l * C_ * C_, Wv + (size_t)l * C_ * C_, wTqkv);
        k_gemm<3><<<dim3(18, 32), 256, 0, stream>>>(h, wTqkv, nullptr, nullptr,
            nullptr, qb_, kb_, vTb, 4096, 3 * C_, C_);
        k_attn<<<dim3(48, 16), 256, 0, stream>>>(qb_, kb_, vTb, yc);
        k_transpose_cvt<<<dim3(24, 24), tb, 0, stream>>>(Wp + (size_t)l * C_ * C_, wTa, C_, C_);
        k_gemm<2><<<dim3(6, 32), 256, 0, stream>>>(yc, wTa, bp + l * C_, x,
            x, nullptr, nullptr, nullptr, 4096, C_, C_);
        k_ln<<<4096, 256, 0, stream>>>(x, ln2s + l * C_, ln2b + l * C_, h);
        k_transpose_cvt<<<dim3(96, 24), tb, 0, stream>>>(W1 + (size_t)l * C_ * F_, wT1, C_, F_);
        k_gemm<1><<<dim3(24, 32), 256, 0, stream>>>(h, wT1, b1 + l * F_, nullptr,
            nullptr, mh, nullptr, nullptr, 4096, F_, C_);
        k_transpose_cvt<<<dim3(24, 96), tb, 0, stream>>>(W2 + (size_t)l * F_ * C_, wT2, F_, C_);
        k_gemm<2><<<dim3(6, 32), 256, 0, stream>>>(mh, wT2, b2 + l * C_, x,
            x, nullptr, nullptr, nullptr, 4096, C_, F_);
    }
    k_ln<<<4096, 256, 0, stream>>>(x, lnfs, lnfb, h);
    k_transpose_cvt<<<dim3(1000, 24), tb, 0, stream>>>(Wh, whT, C_, V_);
    k_gemm<0><<<dim3(250, 32), 256, 0, stream>>>(h, whT, nullptr, nullptr,
        out, nullptr, nullptr, nullptr, 4096, V_, C_);
}

// Round 4
// 1295.679 us; speedup vs baseline: 1.2816x; 1.1103x over previous
//
#include <hip/hip_runtime.h>
#include <stdint.h>

// ---- problem constants (fixed by the reference) ----
#define B_ 4
#define T_ 1024
#define C_ 768
#define H_ 12
#define D_ 64
#define F_ 3072
#define V_ 32000
#define L_ 4

typedef unsigned short ushort_t;
typedef __bf16 bf16x8 __attribute__((ext_vector_type(8)));
typedef float f32x4 __attribute__((ext_vector_type(4)));
typedef unsigned short u16x8 __attribute__((ext_vector_type(8)));

__device__ __forceinline__ float b2f(unsigned short u) {
    union { unsigned int i; float f; } x; x.i = ((unsigned int)u) << 16; return x.f;
}
__device__ __forceinline__ unsigned short f2b(float f) {
    union { float f; unsigned int i; } x; x.f = f;
    unsigned int r = x.i + 0x7FFFu + ((x.i >> 16) & 1u);
    return (unsigned short)(r >> 16);
}

// async global->LDS, 16B per lane; LDS dest = wave-uniform base, HW scatters lane*16B
__device__ __forceinline__ void gload16(const ushort_t* g, ushort_t* l) {
    __builtin_amdgcn_global_load_lds(
        (const __attribute__((address_space(1))) unsigned int*)g,
        (__attribute__((address_space(3))) unsigned int*)l, 16, 0, 0);
}

// ---------------------------------------------------------------------------
// embedding: x[b,t,c] = tok_emb[idx[b,t],c] + pos_emb[t,c]   (all f32)
// ---------------------------------------------------------------------------
__global__ __launch_bounds__(256) void k_embed(const int* __restrict__ idx,
        const float* __restrict__ tok, const float* __restrict__ pos,
        float* __restrict__ x) {
    int i = blockIdx.x * 256 + threadIdx.x;      // chunk of 4 elems
    int m = i / (C_ / 4);
    int cc = (i % (C_ / 4)) * 4;
    int t = m & (T_ - 1);
    int tokid = idx[m];
    float4 te = *(const float4*)&tok[(size_t)tokid * C_ + cc];
    float4 pe = *(const float4*)&pos[(size_t)t * C_ + cc];
    *(float4*)&x[(size_t)m * C_ + cc] =
        make_float4(te.x + pe.x, te.y + pe.y, te.z + pe.z, te.w + pe.w);
}

// ---------------------------------------------------------------------------
// LayerNorm: f32 in -> bf16 out.  one row (768) per block of 256.
// ---------------------------------------------------------------------------
__global__ __launch_bounds__(256) void k_ln(const float* __restrict__ x,
        const float* __restrict__ s, const float* __restrict__ b,
        ushort_t* __restrict__ out) {
    __shared__ float red[8];
    const int row = blockIdx.x, tid = threadIdx.x;
    const float* xr = x + (size_t)row * C_;
    float v[3];
    float sum = 0.f, sq = 0.f;
#pragma unroll
    for (int j = 0; j < 3; ++j) { v[j] = xr[tid + j * 256]; sum += v[j]; sq += v[j] * v[j]; }
#pragma unroll
    for (int off = 32; off >= 1; off >>= 1) {
        sum += __shfl_down(sum, off);
        sq  += __shfl_down(sq,  off);
    }
    const int lane = tid & 63, wave = tid >> 6;
    if (lane == 0) { red[wave] = sum; red[4 + wave] = sq; }
    __syncthreads();
    if (tid < 2) {
        float a = red[tid * 4] + red[tid * 4 + 1] + red[tid * 4 + 2] + red[tid * 4 + 3];
        red[tid * 4] = a;
    }
    __syncthreads();
    float mean = red[0] * (1.f / C_);
    float var  = red[4] * (1.f / C_) - mean * mean;
    float rstd = rsqrtf(var + 1e-5f);
#pragma unroll
    for (int j = 0; j < 3; ++j) {
        int c = tid + j * 256;
        out[(size_t)row * C_ + c] = f2b((v[j] - mean) * rstd * s[c] + b[c]);
    }
}

// ---------------------------------------------------------------------------
// weight transpose+convert: f32 [R,C] -> bf16 [C,R].  block (32,8), 32x32 tiles.
// ---------------------------------------------------------------------------
__global__ void k_transpose_cvt(const float* __restrict__ in, ushort_t* __restrict__ out,
                                int R, int C) {
    __shared__ float tile[32][33];
    int r0 = blockIdx.y * 32, c0 = blockIdx.x * 32;
    int tx = threadIdx.x, ty = threadIdx.y;
#pragma unroll
    for (int i = ty; i < 32; i += 8)
        tile[i][tx] = in[(size_t)(r0 + i) * C + c0 + tx];
    __syncthreads();
#pragma unroll
    for (int i = ty; i < 32; i += 8)
        out[(size_t)(c0 + i) * R + r0 + tx] = f2b(tile[tx][i]);
}

// batched 3-source version for Wq/Wk/Wv -> one [2304, 768] bf16 buffer
__global__ void k_transpose_cvt3(const float* __restrict__ w0, const float* __restrict__ w1,
                                 const float* __restrict__ w2, ushort_t* __restrict__ out) {
    __shared__ float tile[32][33];
    const float* in = (blockIdx.z == 0) ? w0 : (blockIdx.z == 1) ? w1 : w2;
    ushort_t* o = out + (size_t)blockIdx.z * C_ * C_;
    int r0 = blockIdx.y * 32, c0 = blockIdx.x * 32;
    int tx = threadIdx.x, ty = threadIdx.y;
#pragma unroll
    for (int i = ty; i < 32; i += 8)
        tile[i][tx] = in[(size_t)(r0 + i) * C_ + c0 + tx];
    __syncthreads();
#pragma unroll
    for (int i = ty; i < 32; i += 8)
        o[(size_t)(c0 + i) * C_ + r0 + tx] = f2b(tile[tx][i]);
}

// ---------------------------------------------------------------------------
// GEMM  C[M,N] = A[M,K] @ BT[N,K]^T  (bf16, K-contiguous), MFMA 16x16x32
// 128x128 tile, BK=32, 4 waves (2x2), 2-phase double-buffered global_load_lds,
// slot-XOR LDS swizzle (pre-swizzled global source + swizzled ds_read),
// XCD-chunked block swizzle (grid divisible by 8).
// EPI: 0 = f32 NT store (head)    1 = +bias, GELU(exact), bf16 store
//      2 = +bias +resid(f32), f32 store (in-place x ok)
//      3 = QKV 3-way scatter: q,k -> [B,H,T,D], v -> [B,H,D,T] (transposed)
// ---------------------------------------------------------------------------
template <int EPI>
__global__ __launch_bounds__(256) void k_gemm(
        const ushort_t* __restrict__ A, const ushort_t* __restrict__ BT,
        const float* __restrict__ bias, const float* __restrict__ resid,
        float* __restrict__ outf, ushort_t* __restrict__ outb,
        ushort_t* __restrict__ outb2, ushort_t* __restrict__ outb3,
        int M, int N, int K) {
    __shared__ __align__(16) ushort_t As[2][128 * 32];
    __shared__ __align__(16) ushort_t Bs[2][128 * 32];
    const int tid = threadIdx.x;
    const int lane = tid & 63, wave = tid >> 6;
    const int lr = lane & 15, lg = lane >> 4;
    const int wm = (wave >> 1) * 64, wn = (wave & 1) * 64;

    const int GX = gridDim.x;
    int bid = blockIdx.y * GX + blockIdx.x;
    int cpx = (GX * gridDim.y) >> 3;
    int swz = (bid & 7) * cpx + (bid >> 3);
    const int m0 = (swz / GX) * 128, n0 = (swz % GX) * 128;

    // staging: lane i covers LDS row wave*16+i/4, slot i&3 (HW linear scatter).
    // LDS slot s of row r holds global chunk s ^ ((r>>1)&3)  =>  source chunk
    // for lane i is (i&3) ^ ((i>>3)&3)   [since ((wave*16+(i>>2))>>1)&3 == (i>>3)&3]
    const int sr = wave * 16 + (lane >> 2);
    const int sc = (((lane & 3) ^ ((lane >> 3) & 3)) << 3);

    f32x4 acc[4][4];
#pragma unroll
    for (int i = 0; i < 4; ++i)
#pragma unroll
        for (int j = 0; j < 4; ++j) acc[i][j] = (f32x4){0.f, 0.f, 0.f, 0.f};

    auto stage = [&](int k0, int buf) {
        gload16(&A [(size_t)(m0 + sr)      * K + k0 + sc], &As[buf][(wave * 16) * 32]);
        gload16(&A [(size_t)(m0 + 64 + sr) * K + k0 + sc], &As[buf][(64 + wave * 16) * 32]);
        gload16(&BT[(size_t)(n0 + sr)      * K + k0 + sc], &Bs[buf][(wave * 16) * 32]);
        gload16(&BT[(size_t)(n0 + 64 + sr) * K + k0 + sc], &Bs[buf][(64 + wave * 16) * 32]);
    };

    const int nt = K >> 5;
    stage(0, 0);
    int cur = 0;
    const int swzr = (lr >> 1) & 3;          // read-side slot XOR (= ((row>>1)&3))
    for (int t = 0; t < nt; ++t) {
        asm volatile("s_waitcnt vmcnt(0)" ::: "memory");
        __builtin_amdgcn_sched_barrier(0);
        __builtin_amdgcn_s_barrier();
        bf16x8 af[4], bfr[4];
#pragma unroll
        for (int i = 0; i < 4; ++i)
            af[i]  = *(const bf16x8*)&As[cur][(wm + i * 16 + lr) * 32 + ((lg ^ swzr) << 3)];
#pragma unroll
        for (int j = 0; j < 4; ++j)
            bfr[j] = *(const bf16x8*)&Bs[cur][(wn + j * 16 + lr) * 32 + ((lg ^ swzr) << 3)];
        if (t + 1 < nt) stage((t + 1) << 5, cur ^ 1);
#pragma unroll
        for (int i = 0; i < 4; ++i)
#pragma unroll
            for (int j = 0; j < 4; ++j)
                acc[i][j] = __builtin_amdgcn_mfma_f32_16x16x32_bf16(af[i], bfr[j], acc[i][j], 0, 0, 0);
        __builtin_amdgcn_s_barrier();
        cur ^= 1;
    }

#pragma unroll
    for (int i = 0; i < 4; ++i) {
#pragma unroll
        for (int j = 0; j < 4; ++j) {
            int col = n0 + wn + j * 16 + lr;
            float bval = 0.f;
            if (EPI == 1 || EPI == 2) bval = bias[col];
#pragma unroll
            for (int r = 0; r < 4; ++r) {
                int row = m0 + wm + i * 16 + lg * 4 + r;
                float v = acc[i][j][r];
                if (EPI == 0) {
                    __builtin_nontemporal_store(v, &outf[(size_t)row * N + col]);
                } else if (EPI == 1) {
                    float u = v + bval;
                    outb[(size_t)row * N + col] =
                        f2b(0.5f * u * (1.0f + erff(u * 0.70710678118654752f)));
                } else if (EPI == 2) {
                    outf[(size_t)row * N + col] = resid[(size_t)row * N + col] + v + bval;
                } else {
                    int nm = col / 768, c = col % 768;
                    int hh = c >> 6, d = c & 63;
                    int bb = row >> 10, t = row & 1023;
                    ushort_t val = f2b(v);
                    if (nm == 0)
                        outb [((((size_t)bb * H_ + hh) << 10) + t) * D_ + d] = val;
                    else if (nm == 1)
                        outb2[((((size_t)bb * H_ + hh) << 10) + t) * D_ + d] = val;
                    else
                        outb3[(((size_t)bb * H_ + hh) * D_ + d) * T_ + t] = val;
                }
            }
        }
    }
}

// ---------------------------------------------------------------------------
// flash attention: q,k [BH,T,D] bf16, vT [BH,D,T] bf16 -> yc [B,T,C] bf16
// block = 4 waves, wave = 16 q rows, KV tiles of 64, online softmax (f32).
// output written directly in concat layout (fuses head-gather).
// ---------------------------------------------------------------------------
__global__ __launch_bounds__(256) void k_attn(const ushort_t* __restrict__ q,
        const ushort_t* __restrict__ k, const ushort_t* __restrict__ vT,
        ushort_t* __restrict__ yc) {
    __shared__ __align__(16) ushort_t P[4][16 * 64];
    const int lane = threadIdx.x & 63, wave = threadIdx.x >> 6;
    const int lr = lane & 15, lg = lane >> 4;
    const int bh = blockIdx.x;
    const int bb = bh / H_, hh = bh % H_;
    const int qrow0 = blockIdx.y * 64 + wave * 16;
    const ushort_t* qb = q + (size_t)bh * T_ * D_;
    const ushort_t* kb = k + (size_t)bh * T_ * D_;
    const ushort_t* vb = vT + (size_t)bh * D_ * T_;

    bf16x8 aq0 = *(const bf16x8*)&qb[(qrow0 + lr) * D_ + lg * 8];
    bf16x8 aq1 = *(const bf16x8*)&qb[(qrow0 + lr) * D_ + 32 + lg * 8];

    f32x4 accY[4];
    float mr[4], ls[4];
#pragma unroll
    for (int d = 0; d < 4; ++d) accY[d] = (f32x4){0.f, 0.f, 0.f, 0.f};
#pragma unroll
    for (int r = 0; r < 4; ++r) { mr[r] = -1e30f; ls[r] = 0.f; }

    ushort_t* pw = &P[wave][0];
    const int kv_end = qrow0 + 16;
    for (int kv0 = 0; kv0 < kv_end; kv0 += 64) {
        f32x4 s[4];
#pragma unroll
        for (int j = 0; j < 4; ++j) s[j] = (f32x4){0.f, 0.f, 0.f, 0.f};
#pragma unroll
        for (int j = 0; j < 4; ++j) {
            bf16x8 bk0 = *(const bf16x8*)&kb[(kv0 + j * 16 + lr) * D_ + lg * 8];
            bf16x8 bk1 = *(const bf16x8*)&kb[(kv0 + j * 16 + lr) * D_ + 32 + lg * 8];
            s[j] = __builtin_amdgcn_mfma_f32_16x16x32_bf16(aq0, bk0, s[j], 0, 0, 0);
            s[j] = __builtin_amdgcn_mfma_f32_16x16x32_bf16(aq1, bk1, s[j], 0, 0, 0);
        }

        float p[4][4], so[4];
#pragma unroll
        for (int r = 0; r < 4; ++r) {
            int row = qrow0 + lg * 4 + r;
            float a[4];
            float t = -1e30f;
#pragma unroll
            for (int j = 0; j < 4; ++j) {
                int col = kv0 + j * 16 + lr;
                a[j] = (col <= row) ? s[j][r] * 0.125f : -1e30f;
                t = fmaxf(t, a[j]);
            }
            t = fmaxf(t, __shfl_xor(t, 1));
            t = fmaxf(t, __shfl_xor(t, 2));
            t = fmaxf(t, __shfl_xor(t, 4));
            t = fmaxf(t, __shfl_xor(t, 8));
            float mn = fmaxf(mr[r], t);
            so[r] = __expf(mr[r] - mn);
            float ps = 0.f;
#pragma unroll
            for (int j = 0; j < 4; ++j) { p[j][r] = __expf(a[j] - mn); ps += p[j][r]; }
            ps += __shfl_xor(ps, 1);
            ps += __shfl_xor(ps, 2);
            ps += __shfl_xor(ps, 4);
            ps += __shfl_xor(ps, 8);
            ls[r] = ls[r] * so[r] + ps;
            mr[r] = mn;
        }
#pragma unroll
        for (int d = 0; d < 4; ++d)
#pragma unroll
            for (int r = 0; r < 4; ++r) accY[d][r] *= so[r];

        // previous iter's P read must be complete before overwrite
        asm volatile("s_waitcnt lgkmcnt(0)" ::: "memory");
        __builtin_amdgcn_sched_barrier(0);
#pragma unroll
        for (int r = 0; r < 4; ++r)
#pragma unroll
            for (int j = 0; j < 4; ++j)
                pw[(lg * 4 + r) * 64 + j * 16 + lr] = f2b(p[j][r]);
        asm volatile("s_waitcnt lgkmcnt(0)" ::: "memory");
        __builtin_amdgcn_sched_barrier(0);
        bf16x8 pa0 = *(const bf16x8*)&pw[lr * 64 + lg * 8];
        bf16x8 pa1 = *(const bf16x8*)&pw[lr * 64 + 32 + lg * 8];
#pragma unroll
        for (int d = 0; d < 4; ++d) {
            bf16x8 bv0 = *(const bf16x8*)&vb[(d * 16 + lr) * T_ + kv0 + lg * 8];
            bf16x8 bv1 = *(const bf16x8*)&vb[(d * 16 + lr) * T_ + kv0 + 32 + lg * 8];
            accY[d] = __builtin_amdgcn_mfma_f32_16x16x32_bf16(pa0, bv0, accY[d], 0, 0, 0);
            accY[d] = __builtin_amdgcn_mfma_f32_16x16x32_bf16(pa1, bv1, accY[d], 0, 0, 0);
        }
    }
    float inv[4];
#pragma unroll
    for (int r = 0; r < 4; ++r) inv[r] = 1.0f / ls[r];
#pragma unroll
    for (int d = 0; d < 4; ++d)
#pragma unroll
        for (int r = 0; r < 4; ++r) {
            int row = qrow0 + lg * 4 + r;
            yc[((size_t)bb * T_ + row) * C_ + hh * D_ + d * 16 + lr] = f2b(accY[d][r] * inv[r]);
        }
}

// ---------------------------------------------------------------------------
extern "C" void kernel_launch(void* const* d_in, const int* in_sizes, int n_in,
                              void* d_out, int out_size, void* d_ws, size_t ws_size,
                              hipStream_t stream) {
    (void)in_sizes; (void)n_in; (void)out_size; (void)ws_size;
    const int*   idx  = (const int*)d_in[0];
    const float* tok  = (const float*)d_in[1];
    const float* pos  = (const float*)d_in[2];
    const float* Wq   = (const float*)d_in[3];
    const float* Wk   = (const float*)d_in[4];
    const float* Wv   = (const float*)d_in[5];
    const float* Wp   = (const float*)d_in[6];
    const float* bp   = (const float*)d_in[7];
    const float* ln1s = (const float*)d_in[8];
    const float* ln1b = (const float*)d_in[9];
    const float* ln2s = (const float*)d_in[10];
    const float* ln2b = (const float*)d_in[11];
    const float* W1   = (const float*)d_in[12];
    const float* b1   = (const float*)d_in[13];
    const float* W2   = (const float*)d_in[14];
    const float* b2   = (const float*)d_in[15];
    const float* lnfs = (const float*)d_in[16];
    const float* lnfb = (const float*)d_in[17];
    const float* Wh   = (const float*)d_in[18];
    float* out = (float*)d_out;

    char* ws = (char*)d_ws;
    size_t off = 0;
    auto alloc = [&](size_t bytes) { void* p = ws + off; off += (bytes + 255) & ~(size_t)255; return p; };

    ushort_t* wTqkv = (ushort_t*)alloc((size_t)3 * C_ * C_ * 2);  // [2304,768]
    ushort_t* wTa   = (ushort_t*)alloc((size_t)C_ * C_ * 2);      // proj slot
    ushort_t* wT1   = (ushort_t*)alloc((size_t)C_ * F_ * 2);
    ushort_t* wT2   = (ushort_t*)alloc((size_t)F_ * C_ * 2);
    ushort_t* whT   = (ushort_t*)alloc((size_t)C_ * V_ * 2);
    float*    x     = (float*)   alloc((size_t)B_ * T_ * C_ * 4);
    ushort_t* h     = (ushort_t*)alloc((size_t)B_ * T_ * C_ * 2);
    ushort_t* qb_   = (ushort_t*)alloc((size_t)B_ * T_ * C_ * 2);
    ushort_t* kb_   = (ushort_t*)alloc((size_t)B_ * T_ * C_ * 2);
    ushort_t* vTb   = (ushort_t*)alloc((size_t)B_ * T_ * C_ * 2);
    ushort_t* yc    = (ushort_t*)alloc((size_t)B_ * T_ * C_ * 2);
    ushort_t* mh    = (ushort_t*)alloc((size_t)B_ * T_ * F_ * 2);

    dim3 tb(32, 8);
    k_embed<<<3072, 256, 0, stream>>>(idx, tok, pos, x);

    for (int l = 0; l < L_; ++l) {
        k_ln<<<4096, 256, 0, stream>>>(x, ln1s + l * C_, ln1b + l * C_, h);
        k_transpose_cvt3<<<dim3(24, 24, 3), tb, 0, stream>>>(
            Wq + (size_t)l * C_ * C_, Wk + (size_t)l * C_ * C_, Wv + (size_t)l * C_ * C_, wTqkv);
        k_gemm<3><<<dim3(18, 32), 256, 0, stream>>>(h, wTqkv, nullptr, nullptr,
            nullptr, qb_, kb_, vTb, 4096, 3 * C_, C_);
        k_attn<<<dim3(48, 16), 256, 0, stream>>>(qb_, kb_, vTb, yc);
        k_transpose_cvt<<<dim3(24, 24), tb, 0, stream>>>(Wp + (size_t)l * C_ * C_, wTa, C_, C_);
        k_gemm<2><<<dim3(6, 32), 256, 0, stream>>>(yc, wTa, bp + l * C_, x,
            x, nullptr, nullptr, nullptr, 4096, C_, C_);
        k_ln<<<4096, 256, 0, stream>>>(x, ln2s + l * C_, ln2b + l * C_, h);
        k_transpose_cvt<<<dim3(96, 24), tb, 0, stream>>>(W1 + (size_t)l * C_ * F_, wT1, C_, F_);
        k_gemm<1><<<dim3(24, 32), 256, 0, stream>>>(h, wT1, b1 + l * F_, nullptr,
            nullptr, mh, nullptr, nullptr, 4096, F_, C_);
        k_transpose_cvt<<<dim3(24, 96), tb, 0, stream>>>(W2 + (size_t)l * F_ * C_, wT2, F_, C_);
        k_gemm<2><<<dim3(6, 32), 256, 0, stream>>>(mh, wT2, b2 + l * C_, x,
            x, nullptr, nullptr, nullptr, 4096, C_, F_);
    }
    k_ln<<<4096, 256, 0, stream>>>(x, lnfs, lnfb, h);
    k_transpose_cvt<<<dim3(1000, 24), tb, 0, stream>>>(Wh, whT, C_, V_);
    k_gemm<0><<<dim3(250, 32), 256, 0, stream>>>(h, whT, nullptr, nullptr,
        out, nullptr, nullptr, nullptr, 4096, V_, C_);
}